// Round 4
// baseline (3277.158 us; speedup 1.0000x reference)
//
#include <hip/hip_runtime.h>
#include <hip/hip_bf16.h>

// GCN 4-layer, linear network => collapse to:
// out = A^4 x0 * c4 + A^3 1 * c3 + A^2 1 * c2 + A 1 * c1 + b4
// where A = D^-1/2 (Adj+I) D^-1/2, c4=W1W2W3W4, c3=b1W2W3W4, c2=b2W3W4, c1=b3W4.
// Propagate in scaled space s = D^-1/2 v : s' = D^-1 (A+I) s  (edge weight == 1).
// Dtypes (R1-R3 post-mortems, verified): read_length int32 (probe-confirmed),
// edge_index int32, W/b float32 (bf16 read gave NaN), OUTPUT float32
// (bf16 write gave the exact half-filled/odd-channel error signature; harness
// label "(bf16,...)" is hard-coded text, not a dtype indicator).

#define BLK 256

// If rl were int64 (values in [0,20000)), every odd int32 word is 0.
__global__ void probe_i64(const int* __restrict__ rl32, int* __restrict__ flag) {
    int acc = 0;
    for (int k = threadIdx.x; k < 1024; k += blockDim.x)
        acc |= rl32[2 * k + 1];
    if (acc != 0) atomicOr(flag, 1);   // 1 => int32 layout
}

__global__ void count_deg(const int* __restrict__ dst, float* __restrict__ cnt, int E) {
    int e = blockIdx.x * blockDim.x + threadIdx.x;
    if (e < E) atomicAdd(&cnt[dst[e]], 1.0f);
}

__global__ void init_nodes(const int* __restrict__ rl, const float* __restrict__ cnt,
                           float* __restrict__ dinv, float* __restrict__ sA,
                           float* __restrict__ sB, const int* __restrict__ flag, int N) {
    int i = blockIdx.x * blockDim.x + threadIdx.x;
    if (i < N) {
        int v = (*flag) ? rl[i]        // int32 buffer (confirmed path)
                        : rl[2 * i];   // int64 buffer, little-endian low word
        float d  = cnt[i] + 1.0f;          // degree incl. self-loop
        dinv[i]  = 1.0f / d;
        float rs = rsqrtf(d);
        sB[i] = rs;                        // D^-1/2 * ones
        sA[i] = rs * ((float)v * (1.0f / 20000.0f)); // D^-1/2 * x0
    }
}

__global__ void coeffs(const float* __restrict__ W1, const float* __restrict__ b1,
                       const float* __restrict__ W2, const float* __restrict__ b2,
                       const float* __restrict__ W3, const float* __restrict__ b3,
                       const float* __restrict__ W4, const float* __restrict__ b4,
                       float* __restrict__ c) {
    __shared__ float p3[16], q3[16], r3[16];
    int t = threadIdx.x;
    if (t == 0) {
        float p2[8], q2[8];
        for (int j = 0; j < 8; ++j) {
            float s1 = 0.f, s2 = 0.f;
            for (int k = 0; k < 4; ++k) {
                float w = W2[k * 8 + j];
                s1 += W1[k] * w;
                s2 += b1[k] * w;
            }
            p2[j] = s1; q2[j] = s2;
        }
        for (int m = 0; m < 16; ++m) {
            float s1 = 0.f, s2 = 0.f, s3 = 0.f;
            for (int j = 0; j < 8; ++j) {
                float w = W3[j * 16 + m];
                s1 += p2[j] * w; s2 += q2[j] * w;
                s3 += b2[j] * w;
            }
            p3[m] = s1; q3[m] = s2; r3[m] = s3;
        }
    }
    __syncthreads();
    if (t < 32) {
        float c4 = 0.f, c3 = 0.f, c2 = 0.f, c1 = 0.f;
        for (int k = 0; k < 16; ++k) {
            float w = W4[k * 32 + t];
            c4 += p3[k] * w; c3 += q3[k] * w; c2 += r3[k] * w;
            c1 += b3[k] * w;
        }
        c[t] = c4; c[32 + t] = c3; c[64 + t] = c2; c[96 + t] = c1;
    }
}

__global__ void prop2(const int* __restrict__ src, const int* __restrict__ dst,
                      const float* __restrict__ sA, const float* __restrict__ sB,
                      float* __restrict__ aggA, float* __restrict__ aggB, int E) {
    int e = blockIdx.x * blockDim.x + threadIdx.x;
    if (e < E) {
        int s = src[e], d = dst[e];
        float a = sA[s], b = sB[s];
        atomicAdd(&aggA[d], a);
        atomicAdd(&aggB[d], b);
    }
}

__global__ void update2(float* __restrict__ sA, float* __restrict__ sB,
                        const float* __restrict__ aggA, const float* __restrict__ aggB,
                        const float* __restrict__ dinv, float* __restrict__ zsave, int N) {
    int i = blockIdx.x * blockDim.x + threadIdx.x;
    if (i < N) {
        float di = dinv[i];
        float a = (aggA[i] + sA[i]) * di;
        float b = (aggB[i] + sB[i]) * di;
        sA[i] = a; sB[i] = b;
        zsave[i] = b;
    }
}

__global__ void prop1(const int* __restrict__ src, const int* __restrict__ dst,
                      const float* __restrict__ sA, float* __restrict__ aggA, int E) {
    int e = blockIdx.x * blockDim.x + threadIdx.x;
    if (e < E) {
        atomicAdd(&aggA[dst[e]], sA[src[e]]);
    }
}

__global__ void update1(float* __restrict__ sA, const float* __restrict__ aggA,
                        const float* __restrict__ dinv, int N) {
    int i = blockIdx.x * blockDim.x + threadIdx.x;
    if (i < N) {
        sA[i] = (aggA[i] + sA[i]) * dinv[i];
    }
}

__global__ void write_out(const float* __restrict__ sA, const float* __restrict__ z1,
                          const float* __restrict__ z2, const float* __restrict__ z3,
                          const float* __restrict__ dinv, const float* __restrict__ c,
                          const float* __restrict__ b4,
                          float* __restrict__ out, int N) {
    int t = blockIdx.x * blockDim.x + threadIdx.x;
    int i = t >> 5, f = t & 31;
    if (i < N) {
        float sq = rsqrtf(dinv[i]);  // = sqrt(deg)
        float v = sq * (sA[i] * c[f] + z3[i] * c[32 + f] + z2[i] * c[64 + f]
                        + z1[i] * c[96 + f])
                  + b4[f];
        out[(size_t)i * 32 + f] = v;
    }
}

extern "C" void kernel_launch(void* const* d_in, const int* in_sizes, int n_in,
                              void* d_out, int out_size, void* d_ws, size_t ws_size,
                              hipStream_t stream) {
    const int N = in_sizes[0];
    const int E = in_sizes[1] / 2;
    const int* rl  = (const int*)d_in[0];
    const int* src = (const int*)d_in[1];
    const int* dst = src + E;
    const float* W1 = (const float*)d_in[2];
    const float* b1 = (const float*)d_in[3];
    const float* W2 = (const float*)d_in[4];
    const float* b2 = (const float*)d_in[5];
    const float* W3 = (const float*)d_in[6];
    const float* b3 = (const float*)d_in[7];
    const float* W4 = (const float*)d_in[8];
    const float* b4 = (const float*)d_in[9];

    float* ws   = (float*)d_ws;
    float* dinv = ws;
    float* sA   = dinv + N;
    float* sB   = sA + N;
    float* aggA = sB + N;
    float* aggB = aggA + N;   // contiguous with aggA for one memset
    float* z1   = aggB + N;
    float* z2   = z1 + N;
    float* z3   = z2 + N;
    float* c    = z3 + N;     // 128 floats
    int*   flag = (int*)(c + 128);

    const int gbE = (E + BLK - 1) / BLK;
    const int gbN = (N + BLK - 1) / BLK;

    hipMemsetAsync(flag, 0, sizeof(int), stream);
    probe_i64<<<1, BLK, 0, stream>>>(rl, flag);

    // degree (counted into aggA, consumed by init before agg reuse)
    hipMemsetAsync(aggA, 0, (size_t)N * sizeof(float), stream);
    count_deg<<<gbE, BLK, 0, stream>>>(dst, aggA, E);
    init_nodes<<<gbN, BLK, 0, stream>>>(rl, aggA, dinv, sA, sB, flag, N);
    coeffs<<<1, 64, 0, stream>>>(W1, b1, W2, b2, W3, b3, W4, b4, c);

    float* zs[3] = {z1, z2, z3};
    for (int k = 0; k < 3; ++k) {
        hipMemsetAsync(aggA, 0, (size_t)N * 2 * sizeof(float), stream);
        prop2<<<gbE, BLK, 0, stream>>>(src, dst, sA, sB, aggA, aggB, E);
        update2<<<gbN, BLK, 0, stream>>>(sA, sB, aggA, aggB, dinv, zs[k], N);
    }
    hipMemsetAsync(aggA, 0, (size_t)N * sizeof(float), stream);
    prop1<<<gbE, BLK, 0, stream>>>(src, dst, sA, aggA, E);
    update1<<<gbN, BLK, 0, stream>>>(sA, aggA, dinv, N);

    write_out<<<(N * 32 + BLK - 1) / BLK, BLK, 0, stream>>>(
        sA, z1, z2, z3, dinv, c, b4, (float*)d_out, N);
}

// Round 5
// 927.055 us; speedup vs baseline: 3.5350x; 3.5350x over previous
//
#include <hip/hip_runtime.h>
#include <hip/hip_bf16.h>

// GCN 4-layer, linear network => collapse to:
// out = A^4 x0 * c4 + A^3 1 * c3 + A^2 1 * c2 + A 1 * c1 + b4,
// A = D^-1/2 (Adj+I) D^-1/2. Propagate in scaled space u' = D^-1 (Adj+I) u,
// epilogue multiplies sqrt(deg). Channels (x-path, ones-path) packed float2.
//
// Dtypes (R1-R4 verified): read_length int32, edge_index int32, W/b float32,
// output float32.
//
// R5: replace 8 atomic passes (64M fp32 atomics, 32B/atomic write-through =
// the R4 bottleneck: prop2 WRITE_SIZE 500MB, 773us each) with CSR-build
// (ONE 8M-int-atomic pass; atomicAdd's return value doubles as the edge's
// slot rank) + 4 atomic-free gather passes with register accumulation.
// rank[] and adj[] (32MB each) live in d_out, which is scratch until the
// final write_out.

#define BLK 256

// If rl were int64 (values in [0,20000)), every odd int32 word is 0.
__global__ void probe_i64(const int* __restrict__ rl32, int* __restrict__ flag) {
    int acc = 0;
    for (int k = threadIdx.x; k < 1024; k += blockDim.x)
        acc |= rl32[2 * k + 1];
    if (acc != 0) atomicOr(flag, 1);   // 1 => int32 layout
}

// histogram in-degree AND record each edge's rank within its dst bucket
__global__ void hist_rank(const int* __restrict__ dst, int* __restrict__ cnt,
                          int* __restrict__ rank, int E) {
    int e = blockIdx.x * blockDim.x + threadIdx.x;
    if (e < E) rank[e] = atomicAdd(&cnt[dst[e]], 1);
}

// ---- 3-kernel exclusive prefix scan of cnt[N] -> rowp[N+1] (2048 elems/block)
__global__ void block_totals(const int* __restrict__ cnt, int* __restrict__ aux, int N) {
    __shared__ int sm[BLK];
    int b = blockIdx.x, t = threadIdx.x;
    int base = b * 2048 + t * 8;
    int s = 0;
#pragma unroll
    for (int k = 0; k < 8; ++k) { int i = base + k; s += (i < N) ? cnt[i] : 0; }
    sm[t] = s; __syncthreads();
    for (int off = BLK / 2; off > 0; off >>= 1) {
        if (t < off) sm[t] += sm[t + off];
        __syncthreads();
    }
    if (t == 0) aux[b] = sm[0];
}

__global__ void scan_aux(int* __restrict__ aux, int B1) {
    __shared__ int sm[BLK];
    int t = threadIdx.x;
    int v = (t < B1) ? aux[t] : 0;
    sm[t] = v; __syncthreads();
    for (int off = 1; off < BLK; off <<= 1) {
        int add = (t >= off) ? sm[t - off] : 0;
        __syncthreads();
        sm[t] += add;
        __syncthreads();
    }
    if (t < B1) aux[t] = sm[t] - v;   // exclusive
}

__global__ void scan_write(const int* __restrict__ cnt, const int* __restrict__ aux,
                           int* __restrict__ rowp, int N, int E) {
    __shared__ int sm[BLK];
    int b = blockIdx.x, t = threadIdx.x;
    int base = b * 2048 + t * 8;
    int c[8]; int s = 0;
#pragma unroll
    for (int k = 0; k < 8; ++k) { int i = base + k; c[k] = (i < N) ? cnt[i] : 0; s += c[k]; }
    sm[t] = s; __syncthreads();
    int v = s;
    for (int off = 1; off < BLK; off <<= 1) {
        int add = (t >= off) ? sm[t - off] : 0;
        __syncthreads();
        sm[t] += add;
        __syncthreads();
    }
    int run = aux[b] + (sm[t] - v);   // exclusive across threads
#pragma unroll
    for (int k = 0; k < 8; ++k) { int i = base + k; if (i < N) rowp[i] = run; run += c[k]; }
    if (b == 0 && t == 0) rowp[N] = E;
}

// adj[slot] = src  (no atomics; slot = row start + precomputed rank)
__global__ void fill_adj(const int* __restrict__ src, const int* __restrict__ dst,
                         const int* __restrict__ rank, const int* __restrict__ rowp,
                         int* __restrict__ adj, int E) {
    int e = blockIdx.x * blockDim.x + threadIdx.x;
    if (e < E) adj[rowp[dst[e]] + rank[e]] = src[e];
}

__global__ void init_nodes(const int* __restrict__ rl, const int* __restrict__ cnt,
                           float* __restrict__ dinv, float2* __restrict__ v0,
                           const int* __restrict__ flag, int N) {
    int i = blockIdx.x * blockDim.x + threadIdx.x;
    if (i < N) {
        int v = (*flag) ? rl[i] : rl[2 * i];
        float d  = (float)cnt[i] + 1.0f;     // in-degree + self-loop
        dinv[i]  = 1.0f / d;
        float rs = rsqrtf(d);
        float2 u; u.x = rs * ((float)v * (1.0f / 20000.0f)); u.y = rs;
        v0[i] = u;
    }
}

__global__ void coeffs(const float* __restrict__ W1, const float* __restrict__ b1,
                       const float* __restrict__ W2, const float* __restrict__ b2,
                       const float* __restrict__ W3, const float* __restrict__ b3,
                       const float* __restrict__ W4, const float* __restrict__ b4,
                       float* __restrict__ c) {
    __shared__ float p3[16], q3[16], r3[16];
    int t = threadIdx.x;
    if (t == 0) {
        float p2[8], q2[8];
        for (int j = 0; j < 8; ++j) {
            float s1 = 0.f, s2 = 0.f;
            for (int k = 0; k < 4; ++k) {
                float w = W2[k * 8 + j];
                s1 += W1[k] * w;
                s2 += b1[k] * w;
            }
            p2[j] = s1; q2[j] = s2;
        }
        for (int m = 0; m < 16; ++m) {
            float s1 = 0.f, s2 = 0.f, s3 = 0.f;
            for (int j = 0; j < 8; ++j) {
                float w = W3[j * 16 + m];
                s1 += p2[j] * w; s2 += q2[j] * w;
                s3 += b2[j] * w;
            }
            p3[m] = s1; q3[m] = s2; r3[m] = s3;
        }
    }
    __syncthreads();
    if (t < 32) {
        float c4 = 0.f, c3 = 0.f, c2 = 0.f, c1 = 0.f;
        for (int k = 0; k < 16; ++k) {
            float w = W4[k * 32 + t];
            c4 += p3[k] * w; c3 += q3[k] * w; c2 += r3[k] * w;
            c1 += b3[k] * w;
        }
        c[t] = c4; c[32 + t] = c3; c[64 + t] = c2; c[96 + t] = c1;
    }
}

// one propagation step, 4 lanes per row, register accumulate, no atomics
__global__ void gather2(const int* __restrict__ rowp, const int* __restrict__ adj,
                        const float2* __restrict__ vin, float2* __restrict__ vout,
                        const float* __restrict__ dinv, float* __restrict__ zsave, int N) {
    int t = blockIdx.x * blockDim.x + threadIdx.x;
    int i = t >> 2, l = t & 3;
    if (i >= N) return;
    int beg = rowp[i], end = rowp[i + 1];
    float a = 0.f, b = 0.f;
    for (int j = beg + l; j < end; j += 4) {
        float2 v = vin[adj[j]];
        a += v.x; b += v.y;
    }
    a += __shfl_xor(a, 1); b += __shfl_xor(b, 1);
    a += __shfl_xor(a, 2); b += __shfl_xor(b, 2);
    if (l == 0) {
        float2 self = vin[i];
        float di = dinv[i];
        float2 o; o.x = (a + self.x) * di; o.y = (b + self.y) * di;
        vout[i] = o;
        if (zsave) zsave[i] = o.y;
    }
}

__global__ void write_out(const float2* __restrict__ v0, const float* __restrict__ z1,
                          const float* __restrict__ z2, const float* __restrict__ z3,
                          const float* __restrict__ dinv, const float* __restrict__ c,
                          const float* __restrict__ b4,
                          float* __restrict__ out, int N) {
    int t = blockIdx.x * blockDim.x + threadIdx.x;
    int i = t >> 5, f = t & 31;
    if (i < N) {
        float sq = rsqrtf(dinv[i]);  // = sqrt(deg)
        float v = sq * (v0[i].x * c[f] + z3[i] * c[32 + f] + z2[i] * c[64 + f]
                        + z1[i] * c[96 + f])
                  + b4[f];
        out[(size_t)i * 32 + f] = v;
    }
}

extern "C" void kernel_launch(void* const* d_in, const int* in_sizes, int n_in,
                              void* d_out, int out_size, void* d_ws, size_t ws_size,
                              hipStream_t stream) {
    const int N = in_sizes[0];
    const int E = in_sizes[1] / 2;
    const int* rl  = (const int*)d_in[0];
    const int* src = (const int*)d_in[1];
    const int* dst = src + E;
    const float* W1 = (const float*)d_in[2];
    const float* b1 = (const float*)d_in[3];
    const float* W2 = (const float*)d_in[4];
    const float* b2 = (const float*)d_in[5];
    const float* W3 = (const float*)d_in[6];
    const float* b3 = (const float*)d_in[7];
    const float* W4 = (const float*)d_in[8];
    const float* b4 = (const float*)d_in[9];

    // workspace: small N-sized arrays (~20 MB)
    float* ws   = (float*)d_ws;
    float*  dinv = ws;                        // N
    float2* v0   = (float2*)(dinv + N);       // 2N floats
    float2* v1   = v0 + N;                    // 2N floats
    float*  z1   = (float*)(v1 + N);          // N
    float*  z2   = z1 + N;                    // N
    float*  z3   = z2 + N;                    // N
    int*    cnt  = (int*)(z3 + N);            // N
    int*    rowp = cnt + N;                   // N+1
    int*    aux  = rowp + N + 1;              // 256
    float*  c    = (float*)(aux + 256);       // 128
    int*    flag = (int*)(c + 128);           // 1

    // big edge arrays live in d_out (scratch until final write_out)
    int* rank = (int*)d_out;                  // E ints (first 32MB)
    int* adj  = rank + E;                     // E ints (second 32MB)

    const int gbE = (E + BLK - 1) / BLK;
    const int gbN = (N + BLK - 1) / BLK;
    const int B1  = (N + 2047) / 2048;        // 245 blocks for N=500K (<=256)

    hipMemsetAsync(flag, 0, sizeof(int), stream);
    probe_i64<<<1, BLK, 0, stream>>>(rl, flag);

    // CSR build: histogram+rank (the single atomic pass), scan, scatter
    hipMemsetAsync(cnt, 0, (size_t)N * sizeof(int), stream);
    hist_rank<<<gbE, BLK, 0, stream>>>(dst, cnt, rank, E);
    block_totals<<<B1, BLK, 0, stream>>>(cnt, aux, N);
    scan_aux<<<1, BLK, 0, stream>>>(aux, B1);
    scan_write<<<B1, BLK, 0, stream>>>(cnt, aux, rowp, N, E);
    fill_adj<<<gbE, BLK, 0, stream>>>(src, dst, rank, rowp, adj, E);

    init_nodes<<<gbN, BLK, 0, stream>>>(rl, cnt, dinv, v0, flag, N);
    coeffs<<<1, 64, 0, stream>>>(W1, b1, W2, b2, W3, b3, W4, b4, c);

    // 4 propagation passes, ping-pong v0<->v1
    const int gbG = (4 * N + BLK - 1) / BLK;
    gather2<<<gbG, BLK, 0, stream>>>(rowp, adj, v0, v1, dinv, z1, N);
    gather2<<<gbG, BLK, 0, stream>>>(rowp, adj, v1, v0, dinv, z2, N);
    gather2<<<gbG, BLK, 0, stream>>>(rowp, adj, v0, v1, dinv, z3, N);
    gather2<<<gbG, BLK, 0, stream>>>(rowp, adj, v1, v0, dinv, (float*)nullptr, N);

    write_out<<<(N * 32 + BLK - 1) / BLK, BLK, 0, stream>>>(
        v0, z1, z2, z3, dinv, c, b4, (float*)d_out, N);
}

// Round 6
// 727.559 us; speedup vs baseline: 4.5043x; 1.2742x over previous
//
#include <hip/hip_runtime.h>
#include <hip/hip_bf16.h>

// GCN 4-layer, linear network => collapse to:
// out = A^4 x0 * c4 + A^3 1 * c3 + A^2 1 * c2 + A 1 * c1 + b4,
// A = D^-1/2 (Adj+I) D^-1/2. Propagate in scaled space u' = D^-1 (Adj+I) u,
// epilogue multiplies sqrt(deg). Channels (x-path, ones-path) packed float2.
// Dtypes (R1-R4 verified): read_length int32, edge_index int32, W/b fp32, out fp32.
//
// R6: kill ALL global atomics (R5: hist_rank 330us pinned at the ~850 GB/s
// fabric-atomic write-through ceiling, WRITE_SIZE 281MB). Two-pass LDS radix
// partition by dst-bucket (2048 buckets x 256 nodes): LDS histogram ->
// coalesced table -> 3 small scans -> LDS-cursor scatter into a packed
// uint32 edge array ((dst&255)<<19 | src; N=500000 < 2^19). Then degree,
// init and all 4 propagation sweeps are block-per-bucket with LDS
// accumulation — every global access coalesced or L2-resident.

#define BLK 256
#define NB  2048          // buckets
#define BSH 8             // bucket = dst >> 8  (256 nodes / bucket)
#define PB  512           // partition blocks

// If rl were int64 (values in [0,20000)), every odd int32 word is 0.
__global__ void probe_i64(const int* __restrict__ rl32, int* __restrict__ flag) {
    int acc = 0;
    for (int k = threadIdx.x; k < 1024; k += blockDim.x)
        acc |= rl32[2 * k + 1];
    if (acc != 0) atomicOr(flag, 1);   // 1 => int32 layout
}

__global__ void bucket_count(const int* __restrict__ dst, int* __restrict__ table, int E) {
    __shared__ int h[NB];
    int j = blockIdx.x, t = threadIdx.x;
    for (int b = t; b < NB; b += BLK) h[b] = 0;
    __syncthreads();
    int chunk = (E + PB - 1) / PB;
    int beg = j * chunk, end = min(beg + chunk, E);
    for (int e = beg + t; e < end; e += BLK)
        atomicAdd(&h[((unsigned)dst[e]) >> BSH], 1);
    __syncthreads();
    for (int b = t; b < NB; b += BLK) table[j * NB + b] = h[b];   // coalesced
}

__global__ void bucket_tot(const int* __restrict__ table, int* __restrict__ tot) {
    int b = blockIdx.x * blockDim.x + threadIdx.x;   // NB threads
    int s = 0;
    for (int j = 0; j < PB; ++j) s += table[j * NB + b];  // coalesced rows
    tot[b] = s;
}

__global__ void scan_base(const int* __restrict__ tot, int* __restrict__ base) {
    __shared__ int sm[BLK];
    int t = threadIdx.x;
    int loc[NB / BLK]; int s = 0;
#pragma unroll
    for (int k = 0; k < NB / BLK; ++k) { loc[k] = tot[t * (NB / BLK) + k]; s += loc[k]; }
    sm[t] = s; __syncthreads();
    int v = s;
    for (int off = 1; off < BLK; off <<= 1) {
        int add = (t >= off) ? sm[t - off] : 0;
        __syncthreads(); sm[t] += add; __syncthreads();
    }
    int run = sm[t] - v;   // exclusive across threads
#pragma unroll
    for (int k = 0; k < NB / BLK; ++k) { base[t * (NB / BLK) + k] = run; run += loc[k]; }
    if (t == BLK - 1) base[NB] = run;   // == E
}

// in-place: table[j][b] := bucket_base[b] + sum_{j'<j} table[j'][b]
__global__ void scan_table(int* __restrict__ table, const int* __restrict__ base) {
    int b = blockIdx.x * blockDim.x + threadIdx.x;
    int run = base[b];
    for (int j = 0; j < PB; ++j) {       // coalesced read+write per j
        int v = table[j * NB + b];
        table[j * NB + b] = run;
        run += v;
    }
}

__global__ void scatter(const int* __restrict__ src, const int* __restrict__ dst,
                        const int* __restrict__ table, unsigned* __restrict__ epart, int E) {
    __shared__ int cur[NB];
    int j = blockIdx.x, t = threadIdx.x;
    for (int b = t; b < NB; b += BLK) cur[b] = table[j * NB + b];
    __syncthreads();
    int chunk = (E + PB - 1) / PB;
    int beg = j * chunk, end = min(beg + chunk, E);
    for (int e = beg + t; e < end; e += BLK) {
        unsigned d = (unsigned)dst[e];
        int slot = atomicAdd(&cur[d >> BSH], 1);          // LDS cursor
        epart[slot] = ((d & 255u) << 19) | (unsigned)src[e];
    }
}

// per-bucket degree + node init (deg = in-count + 1 self-loop)
__global__ void bucket_init(const unsigned* __restrict__ epart, const int* __restrict__ base,
                            const int* __restrict__ rl, const int* __restrict__ flag,
                            float* __restrict__ dinv, float2* __restrict__ v0, int N) {
    __shared__ int cnt[256];
    int b = blockIdx.x, t = threadIdx.x;
    cnt[t] = 0;
    __syncthreads();
    int beg = base[b], end = base[b + 1];
    for (int e = beg + t; e < end; e += BLK)
        atomicAdd(&cnt[epart[e] >> 19], 1);
    __syncthreads();
    int node = b * 256 + t;
    if (node < N) {
        int v = (*flag) ? rl[node] : rl[2 * node];
        float d = (float)cnt[t] + 1.0f;
        dinv[node] = 1.0f / d;
        float rs = rsqrtf(d);
        float2 u; u.x = rs * ((float)v * (1.0f / 20000.0f)); u.y = rs;
        v0[node] = u;
    }
}

__global__ void coeffs(const float* __restrict__ W1, const float* __restrict__ b1,
                       const float* __restrict__ W2, const float* __restrict__ b2,
                       const float* __restrict__ W3, const float* __restrict__ b3,
                       const float* __restrict__ W4, const float* __restrict__ b4,
                       float* __restrict__ c) {
    __shared__ float p3[16], q3[16], r3[16];
    int t = threadIdx.x;
    if (t == 0) {
        float p2[8], q2[8];
        for (int j = 0; j < 8; ++j) {
            float s1 = 0.f, s2 = 0.f;
            for (int k = 0; k < 4; ++k) {
                float w = W2[k * 8 + j];
                s1 += W1[k] * w;
                s2 += b1[k] * w;
            }
            p2[j] = s1; q2[j] = s2;
        }
        for (int m = 0; m < 16; ++m) {
            float s1 = 0.f, s2 = 0.f, s3 = 0.f;
            for (int j = 0; j < 8; ++j) {
                float w = W3[j * 16 + m];
                s1 += p2[j] * w; s2 += q2[j] * w;
                s3 += b2[j] * w;
            }
            p3[m] = s1; q3[m] = s2; r3[m] = s3;
        }
    }
    __syncthreads();
    if (t < 32) {
        float c4 = 0.f, c3 = 0.f, c2 = 0.f, c1 = 0.f;
        for (int k = 0; k < 16; ++k) {
            float w = W4[k * 32 + t];
            c4 += p3[k] * w; c3 += q3[k] * w; c2 += r3[k] * w;
            c1 += b3[k] * w;
        }
        c[t] = c4; c[32 + t] = c3; c[64 + t] = c2; c[96 + t] = c1;
    }
}

// one propagation sweep: block per bucket, LDS float accumulation, no atomics
// on global memory; node writes fully coalesced.
__global__ void gather_pass(const unsigned* __restrict__ epart, const int* __restrict__ base,
                            const float2* __restrict__ vin, float2* __restrict__ vout,
                            const float* __restrict__ dinv, float* __restrict__ zsave, int N) {
    __shared__ float accA[256], accB[256];
    int b = blockIdx.x, t = threadIdx.x;
    accA[t] = 0.f; accB[t] = 0.f;
    __syncthreads();
    int beg = base[b], end = base[b + 1];
    for (int e = beg + t; e < end; e += BLK) {
        unsigned p = epart[e];
        float2 v = vin[p & 0x7FFFFu];
        int d = p >> 19;
        atomicAdd(&accA[d], v.x);
        atomicAdd(&accB[d], v.y);
    }
    __syncthreads();
    int node = b * 256 + t;
    if (node < N) {
        float2 self = vin[node];
        float di = dinv[node];
        float2 o; o.x = (accA[t] + self.x) * di; o.y = (accB[t] + self.y) * di;
        vout[node] = o;
        if (zsave) zsave[node] = o.y;
    }
}

__global__ void write_out(const float2* __restrict__ v0, const float* __restrict__ z1,
                          const float* __restrict__ z2, const float* __restrict__ z3,
                          const float* __restrict__ dinv, const float* __restrict__ c,
                          const float* __restrict__ b4,
                          float* __restrict__ out, int N) {
    int t = blockIdx.x * blockDim.x + threadIdx.x;
    int i = t >> 5, f = t & 31;
    if (i < N) {
        float sq = rsqrtf(dinv[i]);  // = sqrt(deg)
        float v = sq * (v0[i].x * c[f] + z3[i] * c[32 + f] + z2[i] * c[64 + f]
                        + z1[i] * c[96 + f])
                  + b4[f];
        out[(size_t)i * 32 + f] = v;
    }
}

extern "C" void kernel_launch(void* const* d_in, const int* in_sizes, int n_in,
                              void* d_out, int out_size, void* d_ws, size_t ws_size,
                              hipStream_t stream) {
    const int N = in_sizes[0];
    const int E = in_sizes[1] / 2;
    const int* rl  = (const int*)d_in[0];
    const int* src = (const int*)d_in[1];
    const int* dst = src + E;
    const float* W1 = (const float*)d_in[2];
    const float* b1 = (const float*)d_in[3];
    const float* W2 = (const float*)d_in[4];
    const float* b2 = (const float*)d_in[5];
    const float* W3 = (const float*)d_in[6];
    const float* b3 = (const float*)d_in[7];
    const float* W4 = (const float*)d_in[8];
    const float* b4 = (const float*)d_in[9];

    // workspace (~20.2 MB)
    float*  dinv = (float*)d_ws;              // N
    float2* v0   = (float2*)(dinv + N);       // 2N floats
    float2* v1   = v0 + N;                    // 2N floats
    float*  z1   = (float*)(v1 + N);          // N
    float*  z2   = z1 + N;                    // N
    float*  z3   = z2 + N;                    // N
    int*    table = (int*)(z3 + N);           // PB*NB ints (4 MB)
    int*    btot  = table + PB * NB;          // NB
    int*    bbase = btot + NB;                // NB+1
    float*  c     = (float*)(bbase + NB + 1); // 128
    int*    flag  = (int*)(c + 128);          // 1

    // packed partitioned edges live in d_out (scratch until write_out)
    unsigned* epart = (unsigned*)d_out;       // E uint32 (32 MB of 64 MB)

    const int gbNode = (N + 255) / 256;       // 1954: covers all buckets w/ nodes

    hipMemsetAsync(flag, 0, sizeof(int), stream);
    probe_i64<<<1, BLK, 0, stream>>>(rl, flag);

    // radix partition by dst bucket — zero global atomics
    bucket_count<<<PB, BLK, 0, stream>>>(dst, table, E);
    bucket_tot<<<NB / BLK, BLK, 0, stream>>>(table, btot);
    scan_base<<<1, BLK, 0, stream>>>(btot, bbase);
    scan_table<<<NB / BLK, BLK, 0, stream>>>(table, bbase);
    scatter<<<PB, BLK, 0, stream>>>(src, dst, table, epart, E);

    bucket_init<<<gbNode, BLK, 0, stream>>>(epart, bbase, rl, flag, dinv, v0, N);
    coeffs<<<1, 64, 0, stream>>>(W1, b1, W2, b2, W3, b3, W4, b4, c);

    // 4 propagation sweeps, ping-pong v0<->v1
    gather_pass<<<gbNode, BLK, 0, stream>>>(epart, bbase, v0, v1, dinv, z1, N);
    gather_pass<<<gbNode, BLK, 0, stream>>>(epart, bbase, v1, v0, dinv, z2, N);
    gather_pass<<<gbNode, BLK, 0, stream>>>(epart, bbase, v0, v1, dinv, z3, N);
    gather_pass<<<gbNode, BLK, 0, stream>>>(epart, bbase, v1, v0, dinv, (float*)nullptr, N);

    write_out<<<(N * 32 + BLK - 1) / BLK, BLK, 0, stream>>>(
        v0, z1, z2, z3, dinv, c, b4, (float*)d_out, N);
}

// Round 7
// 622.901 us; speedup vs baseline: 5.2611x; 1.1680x over previous
//
#include <hip/hip_runtime.h>
#include <hip/hip_bf16.h>

// GCN 4-layer, linear network => collapse to:
// out = A^4 x0 * c4 + A^3 1 * c3 + A^2 1 * c2 + A 1 * c1 + b4,
// A = D^-1/2 (Adj+I) D^-1/2. Propagate in scaled space u' = D^-1 (Adj+I) u,
// epilogue multiplies sqrt(deg). Channels (x-path, ones-path) packed float2.
// Dtypes (R1-R4 verified): read_length int32, edge_index int32, W/b fp32, out fp32.
//
// R7: (a) scatter/bucket_count at BLK=1024 -> 32 waves/CU (R6: 19% occupancy,
// latency-unhidden scattered stores); (b) one-time within-bucket CSR
// (csr_build) -> all 4 sweeps atomic-free, degree comes free from rowp diff
// (bucket_init pass deleted); (c) gather inner loop 4 lanes/node, unrolled x2
// paired loads for MLP (R5/R6 evidence: ~105us/pass regardless of LDS-atomic
// vs register accumulation => bound by dependent gather latency, not atomics).

#define BLK  256
#define SBLK 1024         // scatter/count block (occupancy fix)
#define NB   2048         // buckets
#define BSH  8            // bucket = dst >> 8  (256 nodes / bucket)
#define PB   512          // partition blocks

// If rl were int64 (values in [0,20000)), every odd int32 word is 0.
__global__ void probe_i64(const int* __restrict__ rl32, int* __restrict__ flag) {
    int acc = 0;
    for (int k = threadIdx.x; k < 1024; k += blockDim.x)
        acc |= rl32[2 * k + 1];
    if (acc != 0) atomicOr(flag, 1);   // 1 => int32 layout
}

__global__ __launch_bounds__(SBLK)
void bucket_count(const int* __restrict__ dst, int* __restrict__ table, int E) {
    __shared__ int h[NB];
    int j = blockIdx.x, t = threadIdx.x;
    for (int b = t; b < NB; b += SBLK) h[b] = 0;
    __syncthreads();
    int chunk = (E + PB - 1) / PB;
    int beg = j * chunk, end = min(beg + chunk, E);
    for (int e = beg + t; e < end; e += SBLK)
        atomicAdd(&h[((unsigned)dst[e]) >> BSH], 1);
    __syncthreads();
    for (int b = t; b < NB; b += SBLK) table[j * NB + b] = h[b];   // coalesced
}

__global__ void bucket_tot(const int* __restrict__ table, int* __restrict__ tot) {
    int b = blockIdx.x * blockDim.x + threadIdx.x;   // NB threads
    int s = 0;
    for (int j = 0; j < PB; ++j) s += table[j * NB + b];  // coalesced rows
    tot[b] = s;
}

__global__ void scan_base(const int* __restrict__ tot, int* __restrict__ base) {
    __shared__ int sm[BLK];
    int t = threadIdx.x;
    int loc[NB / BLK]; int s = 0;
#pragma unroll
    for (int k = 0; k < NB / BLK; ++k) { loc[k] = tot[t * (NB / BLK) + k]; s += loc[k]; }
    sm[t] = s; __syncthreads();
    int v = s;
    for (int off = 1; off < BLK; off <<= 1) {
        int add = (t >= off) ? sm[t - off] : 0;
        __syncthreads(); sm[t] += add; __syncthreads();
    }
    int run = sm[t] - v;   // exclusive across threads
#pragma unroll
    for (int k = 0; k < NB / BLK; ++k) { base[t * (NB / BLK) + k] = run; run += loc[k]; }
    if (t == BLK - 1) base[NB] = run;   // == E
}

// in-place: table[j][b] := bucket_base[b] + sum_{j'<j} table[j'][b]
__global__ void scan_table(int* __restrict__ table, const int* __restrict__ base) {
    int b = blockIdx.x * blockDim.x + threadIdx.x;
    int run = base[b];
    for (int j = 0; j < PB; ++j) {       // coalesced read+write per j
        int v = table[j * NB + b];
        table[j * NB + b] = run;
        run += v;
    }
}

__global__ __launch_bounds__(SBLK)
void scatter(const int* __restrict__ src, const int* __restrict__ dst,
             const int* __restrict__ table, unsigned* __restrict__ epart, int E) {
    __shared__ int cur[NB];
    int j = blockIdx.x, t = threadIdx.x;
    for (int b = t; b < NB; b += SBLK) cur[b] = table[j * NB + b];
    __syncthreads();
    int chunk = (E + PB - 1) / PB;
    int beg = j * chunk, end = min(beg + chunk, E);
    for (int e = beg + t; e < end; e += SBLK) {
        unsigned d = (unsigned)dst[e];
        int slot = atomicAdd(&cur[d >> BSH], 1);          // LDS cursor
        epart[slot] = ((d & 255u) << 19) | (unsigned)src[e];
    }
}

// one-time: within each bucket, order edges by local dst node (CSR) and emit
// rowp[node]. Writes land in a 16KB block-local region (L2-merged).
__global__ void csr_build(const unsigned* __restrict__ epart, const int* __restrict__ base,
                          unsigned* __restrict__ epart2, int* __restrict__ rowp) {
    __shared__ int cnt[256];
    __shared__ int sc[256];
    __shared__ int cur[256];
    int b = blockIdx.x, t = threadIdx.x;
    cnt[t] = 0;
    __syncthreads();
    int beg = base[b], end = base[b + 1];
    for (int e = beg + t; e < end; e += 256)
        atomicAdd(&cnt[epart[e] >> 19], 1);
    __syncthreads();
    int v = cnt[t];
    sc[t] = v; __syncthreads();
    for (int off = 1; off < 256; off <<= 1) {
        int add = (t >= off) ? sc[t - off] : 0;
        __syncthreads(); sc[t] += add; __syncthreads();
    }
    int start = beg + sc[t] - v;       // exclusive, global slot
    rowp[b * 256 + t] = start;
    if (t == 255) rowp[b * 256 + 256] = end;   // dup of next block's t=0 (same value)
    cur[t] = start;
    __syncthreads();
    for (int e = beg + t; e < end; e += 256) {
        unsigned p = epart[e];
        int slot = atomicAdd(&cur[p >> 19], 1);
        epart2[slot] = p & 0x7FFFFu;   // just src (19 bits)
    }
}

// node init; in-degree free from rowp
__global__ void init_nodes(const int* __restrict__ rl, const int* __restrict__ rowp,
                           float* __restrict__ dinv, float2* __restrict__ v0,
                           const int* __restrict__ flag, int N) {
    int i = blockIdx.x * blockDim.x + threadIdx.x;
    if (i < N) {
        int v = (*flag) ? rl[i] : rl[2 * i];
        float d = (float)(rowp[i + 1] - rowp[i]) + 1.0f;   // + self-loop
        dinv[i] = 1.0f / d;
        float rs = rsqrtf(d);
        float2 u; u.x = rs * ((float)v * (1.0f / 20000.0f)); u.y = rs;
        v0[i] = u;
    }
}

__global__ void coeffs(const float* __restrict__ W1, const float* __restrict__ b1,
                       const float* __restrict__ W2, const float* __restrict__ b2,
                       const float* __restrict__ W3, const float* __restrict__ b3,
                       const float* __restrict__ W4, const float* __restrict__ b4,
                       float* __restrict__ c) {
    __shared__ float p3[16], q3[16], r3[16];
    int t = threadIdx.x;
    if (t == 0) {
        float p2[8], q2[8];
        for (int j = 0; j < 8; ++j) {
            float s1 = 0.f, s2 = 0.f;
            for (int k = 0; k < 4; ++k) {
                float w = W2[k * 8 + j];
                s1 += W1[k] * w;
                s2 += b1[k] * w;
            }
            p2[j] = s1; q2[j] = s2;
        }
        for (int m = 0; m < 16; ++m) {
            float s1 = 0.f, s2 = 0.f, s3 = 0.f;
            for (int j = 0; j < 8; ++j) {
                float w = W3[j * 16 + m];
                s1 += p2[j] * w; s2 += q2[j] * w;
                s3 += b2[j] * w;
            }
            p3[m] = s1; q3[m] = s2; r3[m] = s3;
        }
    }
    __syncthreads();
    if (t < 32) {
        float c4 = 0.f, c3 = 0.f, c2 = 0.f, c1 = 0.f;
        for (int k = 0; k < 16; ++k) {
            float w = W4[k * 32 + t];
            c4 += p3[k] * w; c3 += q3[k] * w; c2 += r3[k] * w;
            c1 += b3[k] * w;
        }
        c[t] = c4; c[32 + t] = c3; c[64 + t] = c2; c[96 + t] = c1;
    }
}

// one sweep: 4 lanes/node, register accumulate, x2 unrolled paired loads (MLP)
__global__ void gather_csr(const unsigned* __restrict__ epart2, const int* __restrict__ rowp,
                           const float2* __restrict__ vin, float2* __restrict__ vout,
                           const float* __restrict__ dinv, float* __restrict__ zsave, int N) {
    int t = blockIdx.x * blockDim.x + threadIdx.x;
    int i = t >> 2, l = t & 3;
    if (i >= N) return;
    int beg = rowp[i], end = rowp[i + 1];
    float a = 0.f, b = 0.f;
    int j = beg + l;
    for (; j + 4 < end; j += 8) {          // two independent loads in flight
        int s0 = epart2[j];
        int s1 = epart2[j + 4];
        float2 u0 = vin[s0];
        float2 u1 = vin[s1];
        a += u0.x + u1.x; b += u0.y + u1.y;
    }
    if (j < end) {
        float2 u = vin[epart2[j]];
        a += u.x; b += u.y;
    }
    a += __shfl_xor(a, 1); b += __shfl_xor(b, 1);
    a += __shfl_xor(a, 2); b += __shfl_xor(b, 2);
    if (l == 0) {
        float2 self = vin[i];
        float di = dinv[i];
        float2 o; o.x = (a + self.x) * di; o.y = (b + self.y) * di;
        vout[i] = o;
        if (zsave) zsave[i] = o.y;
    }
}

__global__ void write_out(const float2* __restrict__ v0, const float* __restrict__ z1,
                          const float* __restrict__ z2, const float* __restrict__ z3,
                          const float* __restrict__ dinv, const float* __restrict__ c,
                          const float* __restrict__ b4,
                          float* __restrict__ out, int N) {
    int t = blockIdx.x * blockDim.x + threadIdx.x;
    int i = t >> 5, f = t & 31;
    if (i < N) {
        float sq = rsqrtf(dinv[i]);  // = sqrt(deg)
        float v = sq * (v0[i].x * c[f] + z3[i] * c[32 + f] + z2[i] * c[64 + f]
                        + z1[i] * c[96 + f])
                  + b4[f];
        out[(size_t)i * 32 + f] = v;
    }
}

extern "C" void kernel_launch(void* const* d_in, const int* in_sizes, int n_in,
                              void* d_out, int out_size, void* d_ws, size_t ws_size,
                              hipStream_t stream) {
    const int N = in_sizes[0];
    const int E = in_sizes[1] / 2;
    const int* rl  = (const int*)d_in[0];
    const int* src = (const int*)d_in[1];
    const int* dst = src + E;
    const float* W1 = (const float*)d_in[2];
    const float* b1 = (const float*)d_in[3];
    const float* W2 = (const float*)d_in[4];
    const float* b2 = (const float*)d_in[5];
    const float* W3 = (const float*)d_in[6];
    const float* b3 = (const float*)d_in[7];
    const float* W4 = (const float*)d_in[8];
    const float* b4 = (const float*)d_in[9];

    // workspace (~20.1 MB)
    float*  dinv = (float*)d_ws;              // N
    float2* v0   = (float2*)(dinv + N);       // 2N floats
    float2* v1   = v0 + N;                    // 2N floats
    float*  z1   = (float*)(v1 + N);          // N
    float*  z2   = z1 + N;                    // N
    float*  z3   = z2 + N;                    // N
    int*    table = (int*)(z3 + N);           // PB*NB ints (4 MB)
    int*    rowp  = table;                    // aliases table (dead after scatter); N+257 ints
    int*    btot  = table + PB * NB;          // NB
    int*    bbase = btot + NB;                // NB+1
    float*  c     = (float*)(bbase + NB + 1); // 128
    int*    flag  = (int*)(c + 128);          // 1

    // packed edge arrays live in d_out (scratch until write_out)
    unsigned* epart  = (unsigned*)d_out;      // E uint32 (first 32 MB)
    unsigned* epart2 = epart + E;             // E uint32 (second 32 MB)

    const int gbNode = (N + 255) / 256;       // 1954 buckets containing nodes

    hipMemsetAsync(flag, 0, sizeof(int), stream);
    probe_i64<<<1, BLK, 0, stream>>>(rl, flag);

    // radix partition by dst bucket — zero global atomics
    bucket_count<<<PB, SBLK, 0, stream>>>(dst, table, E);
    bucket_tot<<<NB / BLK, BLK, 0, stream>>>(table, btot);
    scan_base<<<1, BLK, 0, stream>>>(btot, bbase);
    scan_table<<<NB / BLK, BLK, 0, stream>>>(table, bbase);
    scatter<<<PB, SBLK, 0, stream>>>(src, dst, table, epart, E);

    // within-bucket CSR (rowp overwrites table — safe, table dead now)
    csr_build<<<gbNode, 256, 0, stream>>>(epart, bbase, epart2, rowp);

    init_nodes<<<(N + BLK - 1) / BLK, BLK, 0, stream>>>(rl, rowp, dinv, v0, flag, N);
    coeffs<<<1, 64, 0, stream>>>(W1, b1, W2, b2, W3, b3, W4, b4, c);

    // 4 propagation sweeps, ping-pong v0<->v1
    const int gbG = (4 * N + BLK - 1) / BLK;
    gather_csr<<<gbG, BLK, 0, stream>>>(epart2, rowp, v0, v1, dinv, z1, N);
    gather_csr<<<gbG, BLK, 0, stream>>>(epart2, rowp, v1, v0, dinv, z2, N);
    gather_csr<<<gbG, BLK, 0, stream>>>(epart2, rowp, v0, v1, dinv, z3, N);
    gather_csr<<<gbG, BLK, 0, stream>>>(epart2, rowp, v1, v0, dinv, (float*)nullptr, N);

    write_out<<<(N * 32 + BLK - 1) / BLK, BLK, 0, stream>>>(
        v0, z1, z2, z3, dinv, c, b4, (float*)d_out, N);
}